// Round 1
// baseline (290.205 us; speedup 1.0000x reference)
//
#include <hip/hip_runtime.h>
#include <stdint.h>

typedef __attribute__((ext_vector_type(4))) float f32x4;
typedef __attribute__((ext_vector_type(8))) short bf16x8;
typedef __attribute__((ext_vector_type(4))) unsigned short u16x4;

constexpr int cB = 4, cS = 4096, cD = 1024, cH = 1024;
constexpr int cM = cB * cS;      // 16384 rows
constexpr int cN = 2 * cH;       // 2048 cols (Wz | Wh)
constexpr int cK = cD;           // 1024
constexpr int NCH = 128;         // scan chunks along S
constexpr int CLEN = cS / NCH;   // 32

__device__ __forceinline__ unsigned short f2bf(float f) {
  union { float f; uint32_t u; } v; v.f = f;
  uint32_t r = v.u + 0x7FFFu + ((v.u >> 16) & 1u);
  return (unsigned short)(r >> 16);
}
__device__ __forceinline__ float bf2f(unsigned short h) {
  union { float f; uint32_t u; } v; v.u = ((uint32_t)h) << 16;
  return v.f;
}

// fp32 -> bf16 hi + bf16 lo (exact residual split)
__global__ void split_kernel(const float* __restrict__ src,
                             unsigned short* __restrict__ hi,
                             unsigned short* __restrict__ lo) {
  int i = (blockIdx.x * blockDim.x + threadIdx.x) * 4;
  f32x4 x = *(const f32x4*)(src + i);
  u16x4 h, l;
#pragma unroll
  for (int j = 0; j < 4; ++j) {
    unsigned short hb = f2bf(x[j]);
    h[j] = hb;
    l[j] = f2bf(x[j] - bf2f(hb));
  }
  *(u16x4*)(hi + i) = h;
  *(u16x4*)(lo + i) = l;
}

// ---------------- GEMM: [16384 x 2048] = x * [Wz;Wh]^T, bf16x3 emulated fp32 ----
constexpr int BM = 128, BN = 128, BK = 64;

__global__ __launch_bounds__(256, 2) void gemm_kernel(
    const unsigned short* __restrict__ xh, const unsigned short* __restrict__ xl,
    const unsigned short* __restrict__ wwh, const unsigned short* __restrict__ wwl,
    const float* __restrict__ bz, const float* __restrict__ bhv,
    float* __restrict__ cbuf, float* __restrict__ gbuf)
{
  __shared__ unsigned short Ah[BM * BK], Al[BM * BK], Bh[BN * BK], Bl[BN * BK];
  const int tid  = threadIdx.x;
  const int lane = tid & 63;
  const int wv   = tid >> 6;
  const int wr   = wv >> 1, wc = wv & 1;
  const int nt = blockIdx.x, mt = blockIdx.y;   // nt fastest -> A-strip L2 sharing
  const int m0 = mt * BM, n0 = nt * BN;
  const int fr = lane & 15, fq = lane >> 4;

  f32x4 acc[4][4] = {};

  // staging: LDS linear dest; source pre-swizzled (rule #21): col ^= (row&7)
  const int srow = tid >> 3;                              // 0..31
  const int scol = (((tid & 7) ^ (srow & 7)) << 3);       // fp16 index

  for (int kt = 0; kt < cK / BK; ++kt) {
    const int k0 = kt * BK;
    __syncthreads();
#pragma unroll
    for (int r = 0; r < 4; ++r) {
      const int row = r * 32 + srow;
      const int ldsoff = r * 4096 + tid * 16;
      const unsigned short* ga_h = xh  + (size_t)(m0 + row) * cK + k0 + scol;
      const unsigned short* ga_l = xl  + (size_t)(m0 + row) * cK + k0 + scol;
      const unsigned short* gb_h = wwh + (size_t)(n0 + row) * cK + k0 + scol;
      const unsigned short* gb_l = wwl + (size_t)(n0 + row) * cK + k0 + scol;
      __builtin_amdgcn_global_load_lds((const __attribute__((address_space(1))) void*)ga_h,
        (__attribute__((address_space(3))) void*)((char*)Ah + ldsoff), 16, 0, 0);
      __builtin_amdgcn_global_load_lds((const __attribute__((address_space(1))) void*)ga_l,
        (__attribute__((address_space(3))) void*)((char*)Al + ldsoff), 16, 0, 0);
      __builtin_amdgcn_global_load_lds((const __attribute__((address_space(1))) void*)gb_h,
        (__attribute__((address_space(3))) void*)((char*)Bh + ldsoff), 16, 0, 0);
      __builtin_amdgcn_global_load_lds((const __attribute__((address_space(1))) void*)gb_l,
        (__attribute__((address_space(3))) void*)((char*)Bl + ldsoff), 16, 0, 0);
    }
    __syncthreads();
#pragma unroll
    for (int kk = 0; kk < BK / 32; ++kk) {
      bf16x8 fa_h[4], fa_l[4], fb_h[4], fb_l[4];
#pragma unroll
      for (int i = 0; i < 4; ++i) {
        const int ar = wr * 64 + i * 16 + fr;
        const int ca = (kk * 64 + fq * 16) ^ ((ar & 7) << 4);   // swizzled read
        fa_h[i] = *(const bf16x8*)((const char*)Ah + ar * 128 + ca);
        fa_l[i] = *(const bf16x8*)((const char*)Al + ar * 128 + ca);
        const int br = wc * 64 + i * 16 + fr;
        const int cbb = (kk * 64 + fq * 16) ^ ((br & 7) << 4);
        fb_h[i] = *(const bf16x8*)((const char*)Bh + br * 128 + cbb);
        fb_l[i] = *(const bf16x8*)((const char*)Bl + br * 128 + cbb);
      }
#pragma unroll
      for (int i = 0; i < 4; ++i)
#pragma unroll
        for (int j = 0; j < 4; ++j) {
          acc[i][j] = __builtin_amdgcn_mfma_f32_16x16x32_bf16(fa_h[i], fb_h[j], acc[i][j], 0, 0, 0);
          acc[i][j] = __builtin_amdgcn_mfma_f32_16x16x32_bf16(fa_h[i], fb_l[j], acc[i][j], 0, 0, 0);
          acc[i][j] = __builtin_amdgcn_mfma_f32_16x16x32_bf16(fa_l[i], fb_h[j], acc[i][j], 0, 0, 0);
        }
    }
  }

  // epilogue: n<1024 -> c = sigmoid(-k); n>=1024 -> g = a>=0 ? a+0.5 : sigmoid(a)
  const bool is_k = (n0 < cH);
#pragma unroll
  for (int j = 0; j < 4; ++j) {
    const int n = n0 + wc * 64 + j * 16 + fr;
    const float bias = is_k ? bz[n] : bhv[n - cH];
#pragma unroll
    for (int i = 0; i < 4; ++i) {
#pragma unroll
      for (int rg = 0; rg < 4; ++rg) {
        const int m = m0 + wr * 64 + i * 16 + fq * 4 + rg;
        const float val = acc[i][j][rg] + bias;
        if (is_k) {
          cbuf[(size_t)m * cH + n] = 1.0f / (1.0f + expf(val));
        } else {
          const float g = (val >= 0.0f) ? (val + 0.5f) : (1.0f / (1.0f + expf(-val)));
          gbuf[(size_t)m * cH + (n - cH)] = g;
        }
      }
    }
  }
}

// ---------------- chunked scan: h_t = c_t*h_{t-1} + (1-c_t)*g_t ------------------
__global__ void scan_chunk_kernel(const float* __restrict__ cbuf, const float* __restrict__ gbuf,
                                  float* __restrict__ Pb, float* __restrict__ Qb) {
  const int bc = blockIdx.x;
  const int b = bc / NCH, ch = bc % NCH;
  const int h4 = threadIdx.x * 4;
  size_t base = ((size_t)b * cS + (size_t)ch * CLEN) * cH + h4;
  f32x4 p = {1.f, 1.f, 1.f, 1.f};
  f32x4 q = {0.f, 0.f, 0.f, 0.f};
#pragma unroll 4
  for (int i = 0; i < CLEN; ++i) {
    f32x4 c = *(const f32x4*)(cbuf + base + (size_t)i * cH);
    f32x4 g = *(const f32x4*)(gbuf + base + (size_t)i * cH);
    q = c * q + (1.0f - c) * g;
    p = p * c;
  }
  size_t o = ((size_t)b * NCH + ch) * cH + h4;
  *(f32x4*)(Pb + o) = p;
  *(f32x4*)(Qb + o) = q;
}

__global__ void scan_prefix_kernel(const float* __restrict__ h0,
                                   const float* __restrict__ Pb, const float* __restrict__ Qb,
                                   float* __restrict__ hin) {
  const int idx = blockIdx.x * blockDim.x + threadIdx.x;  // 0..4095 = b*H+h
  const int b = idx / cH, h = idx % cH;
  float x = h0[idx];
  float hc = (x >= 0.0f) ? (x + 0.5f) : (1.0f / (1.0f + expf(-x)));  // g(h0)
  for (int j = 0; j < NCH; ++j) {
    size_t o = ((size_t)b * NCH + j) * cH + h;
    hin[o] = hc;
    hc = Qb[o] + Pb[o] * hc;
  }
}

// NOTE: gbuf aliases out (g stored in d_out region) -> no __restrict__ on those.
__global__ void scan_write_kernel(const float* __restrict__ cbuf, const float* gbuf,
                                  const float* __restrict__ hin, float* out) {
  const int bc = blockIdx.x;
  const int b = bc / NCH, ch = bc % NCH;
  const int h4 = threadIdx.x * 4;
  f32x4 hc = *(const f32x4*)(hin + ((size_t)b * NCH + ch) * cH + h4);
  size_t base = ((size_t)b * cS + (size_t)ch * CLEN) * cH + h4;
#pragma unroll 4
  for (int i = 0; i < CLEN; ++i) {
    f32x4 c = *(const f32x4*)(cbuf + base + (size_t)i * cH);
    f32x4 g = *(const f32x4*)(gbuf + base + (size_t)i * cH);
    hc = c * hc + (1.0f - c) * g;
    *(f32x4*)(out + base + (size_t)i * cH) = hc;
  }
  if (ch == NCH - 1) {   // final hidden state -> second output
    *(f32x4*)(out + (size_t)cM * cH + (size_t)b * cH + h4) = hc;
  }
}

extern "C" void kernel_launch(void* const* d_in, const int* in_sizes, int n_in,
                              void* d_out, int out_size, void* d_ws, size_t ws_size,
                              hipStream_t stream) {
  const float* x   = (const float*)d_in[0];
  const float* h0  = (const float*)d_in[1];
  const float* Wz  = (const float*)d_in[2];
  const float* bz  = (const float*)d_in[3];
  const float* Wh  = (const float*)d_in[4];
  const float* bh  = (const float*)d_in[5];

  char* ws = (char*)d_ws;
  unsigned short* xh  = (unsigned short*)(ws);              // 32 MiB
  unsigned short* xl  = (unsigned short*)(ws + 33554432);   // 32 MiB
  unsigned short* wwh = (unsigned short*)(ws + 67108864);   // 4 MiB
  unsigned short* wwl = (unsigned short*)(ws + 71303168);   // 4 MiB
  float* cbuf = (float*)(ws + 75497472);                    // 64 MiB
  float* Pb   = (float*)(ws + 142606336);                   // 2 MiB
  float* Qb   = (float*)(ws + 144703488);                   // 2 MiB
  float* hin  = (float*)(ws + 146800640);                   // 2 MiB (end ~142 MiB)
  float* out  = (float*)d_out;
  float* gbuf = out;   // g-values staged in d_out, overwritten by scan_write

  split_kernel<<<cM * cK / 1024, 256, 0, stream>>>(x, xh, xl);
  split_kernel<<<cH * cK / 1024, 256, 0, stream>>>(Wz, wwh, wwl);
  split_kernel<<<cH * cK / 1024, 256, 0, stream>>>(Wh, wwh + (size_t)cH * cK, wwl + (size_t)cH * cK);
  gemm_kernel<<<dim3(cN / 128, cM / 128), 256, 0, stream>>>(xh, xl, wwh, wwl, bz, bh, cbuf, gbuf);
  scan_chunk_kernel<<<cB * NCH, 256, 0, stream>>>(cbuf, gbuf, Pb, Qb);
  scan_prefix_kernel<<<cB * cH / 256, 256, 0, stream>>>(h0, Pb, Qb, hin);
  scan_write_kernel<<<cB * NCH, 256, 0, stream>>>(cbuf, gbuf, hin, out);
}

// Round 2
// 220.163 us; speedup vs baseline: 1.3181x; 1.3181x over previous
//
#include <hip/hip_runtime.h>
#include <stdint.h>

typedef __attribute__((ext_vector_type(4))) float f32x4;
typedef __attribute__((ext_vector_type(8))) short bf16x8;
typedef __attribute__((ext_vector_type(4))) unsigned short u16x4;

constexpr int cB = 4, cS = 4096, cD = 1024, cH = 1024;
constexpr int cM = cB * cS;      // 16384 rows
constexpr int cN = 2 * cH;       // 2048 cols (Wz | Wh)
constexpr int cK = cD;           // 1024
constexpr int NCH = 64;          // scan chunks along S
constexpr int CLEN = cS / NCH;   // 64

__device__ __forceinline__ unsigned short f2bf(float f) {
  union { float f; uint32_t u; } v; v.f = f;
  uint32_t r = v.u + 0x7FFFu + ((v.u >> 16) & 1u);
  return (unsigned short)(r >> 16);
}
__device__ __forceinline__ float bf2f(unsigned short h) {
  union { float f; uint32_t u; } v; v.u = ((uint32_t)h) << 16;
  return v.f;
}

// fp32 -> bf16 (round only, for x; x_lo term dropped: delta_k ~ 6e-4 << budget)
__global__ void round_kernel(const float* __restrict__ src,
                             unsigned short* __restrict__ hi) {
  int i = (blockIdx.x * blockDim.x + threadIdx.x) * 4;
  f32x4 x = *(const f32x4*)(src + i);
  u16x4 h;
#pragma unroll
  for (int j = 0; j < 4; ++j) h[j] = f2bf(x[j]);
  *(u16x4*)(hi + i) = h;
}

// fp32 -> bf16 hi + bf16 lo (exact residual split, for W)
__global__ void split_kernel(const float* __restrict__ src,
                             unsigned short* __restrict__ hi,
                             unsigned short* __restrict__ lo) {
  int i = (blockIdx.x * blockDim.x + threadIdx.x) * 4;
  f32x4 x = *(const f32x4*)(src + i);
  u16x4 h, l;
#pragma unroll
  for (int j = 0; j < 4; ++j) {
    unsigned short hb = f2bf(x[j]);
    h[j] = hb;
    l[j] = f2bf(x[j] - bf2f(hb));
  }
  *(u16x4*)(hi + i) = h;
  *(u16x4*)(lo + i) = l;
}

// ---------------- GEMM: [16384 x 2048] = x_bf * ([Wz;Wh]_hi + [Wz;Wh]_lo)^T ----
constexpr int BM = 128, BN = 128, BK = 64;

__global__ __launch_bounds__(256, 3) void gemm_kernel(
    const unsigned short* __restrict__ xh,
    const unsigned short* __restrict__ wwh, const unsigned short* __restrict__ wwl,
    const float* __restrict__ bz, const float* __restrict__ bhv,
    float* __restrict__ cbuf, float* __restrict__ gbuf)
{
  __shared__ unsigned short Ah[BM * BK], Bh[BN * BK], Bl[BN * BK];
  const int tid  = threadIdx.x;
  const int lane = tid & 63;
  const int wv   = tid >> 6;
  const int wr   = wv >> 1, wc = wv & 1;
  const int nt = blockIdx.x, mt = blockIdx.y;   // nt fastest -> A-strip L2 sharing
  const int m0 = mt * BM, n0 = nt * BN;
  const int fr = lane & 15, fq = lane >> 4;

  f32x4 acc[4][4] = {};

  // staging: LDS linear dest; source pre-swizzled (rule #21): col ^= (row&7)
  const int srow = tid >> 3;                              // 0..31
  const int scol = (((tid & 7) ^ (srow & 7)) << 3);       // bf16 index

  for (int kt = 0; kt < cK / BK; ++kt) {
    const int k0 = kt * BK;
    __syncthreads();
#pragma unroll
    for (int r = 0; r < 4; ++r) {
      const int row = r * 32 + srow;
      const int ldsoff = r * 4096 + tid * 16;
      const unsigned short* ga_h = xh  + (size_t)(m0 + row) * cK + k0 + scol;
      const unsigned short* gb_h = wwh + (size_t)(n0 + row) * cK + k0 + scol;
      const unsigned short* gb_l = wwl + (size_t)(n0 + row) * cK + k0 + scol;
      __builtin_amdgcn_global_load_lds((const __attribute__((address_space(1))) void*)ga_h,
        (__attribute__((address_space(3))) void*)((char*)Ah + ldsoff), 16, 0, 0);
      __builtin_amdgcn_global_load_lds((const __attribute__((address_space(1))) void*)gb_h,
        (__attribute__((address_space(3))) void*)((char*)Bh + ldsoff), 16, 0, 0);
      __builtin_amdgcn_global_load_lds((const __attribute__((address_space(1))) void*)gb_l,
        (__attribute__((address_space(3))) void*)((char*)Bl + ldsoff), 16, 0, 0);
    }
    __syncthreads();
#pragma unroll
    for (int kk = 0; kk < BK / 32; ++kk) {
      bf16x8 fa[4], fb_h[4], fb_l[4];
#pragma unroll
      for (int i = 0; i < 4; ++i) {
        const int ar = wr * 64 + i * 16 + fr;
        const int ca = (kk * 64 + fq * 16) ^ ((ar & 7) << 4);   // swizzled read
        fa[i] = *(const bf16x8*)((const char*)Ah + ar * 128 + ca);
        const int br = wc * 64 + i * 16 + fr;
        const int cbb = (kk * 64 + fq * 16) ^ ((br & 7) << 4);
        fb_h[i] = *(const bf16x8*)((const char*)Bh + br * 128 + cbb);
        fb_l[i] = *(const bf16x8*)((const char*)Bl + br * 128 + cbb);
      }
#pragma unroll
      for (int i = 0; i < 4; ++i)
#pragma unroll
        for (int j = 0; j < 4; ++j) {
          acc[i][j] = __builtin_amdgcn_mfma_f32_16x16x32_bf16(fa[i], fb_h[j], acc[i][j], 0, 0, 0);
          acc[i][j] = __builtin_amdgcn_mfma_f32_16x16x32_bf16(fa[i], fb_l[j], acc[i][j], 0, 0, 0);
        }
    }
  }

  // epilogue: n<1024 -> c = sigmoid(-k); n>=1024 -> g = a>=0 ? a+0.5 : sigmoid(a)
  const bool is_k = (n0 < cH);
#pragma unroll
  for (int j = 0; j < 4; ++j) {
    const int n = n0 + wc * 64 + j * 16 + fr;
    const float bias = is_k ? bz[n] : bhv[n - cH];
#pragma unroll
    for (int i = 0; i < 4; ++i) {
#pragma unroll
      for (int rg = 0; rg < 4; ++rg) {
        const int m = m0 + wr * 64 + i * 16 + fq * 4 + rg;
        const float val = acc[i][j][rg] + bias;
        if (is_k) {
          cbuf[(size_t)m * cH + n] = 1.0f / (1.0f + expf(val));
        } else {
          const float g = (val >= 0.0f) ? (val + 0.5f) : (1.0f / (1.0f + expf(-val)));
          gbuf[(size_t)m * cH + (n - cH)] = g;
        }
      }
    }
  }
}

// ---------------- chunked scan: h_t = c_t*h_{t-1} + (1-c_t)*g_t ------------------
__global__ void scan_chunk_kernel(const float* __restrict__ cbuf, const float* __restrict__ gbuf,
                                  float* __restrict__ Pb, float* __restrict__ Qb) {
  const int bc = blockIdx.x;
  const int b = bc / NCH, ch = bc % NCH;
  const int h4 = threadIdx.x * 4;
  size_t base = ((size_t)b * cS + (size_t)ch * CLEN) * cH + h4;
  f32x4 p = {1.f, 1.f, 1.f, 1.f};
  f32x4 q = {0.f, 0.f, 0.f, 0.f};
#pragma unroll 4
  for (int i = 0; i < CLEN; ++i) {
    f32x4 c = *(const f32x4*)(cbuf + base + (size_t)i * cH);
    f32x4 g = *(const f32x4*)(gbuf + base + (size_t)i * cH);
    q = c * q + (1.0f - c) * g;
    p = p * c;
  }
  size_t o = ((size_t)b * NCH + ch) * cH + h4;
  *(f32x4*)(Pb + o) = p;
  *(f32x4*)(Qb + o) = q;
}

__global__ void scan_prefix_kernel(const float* __restrict__ h0,
                                   const float* __restrict__ Pb, const float* __restrict__ Qb,
                                   float* __restrict__ hin) {
  const int idx = blockIdx.x * blockDim.x + threadIdx.x;  // 0..4095 = b*H+h
  const int b = idx / cH, h = idx % cH;
  float x = h0[idx];
  float hc = (x >= 0.0f) ? (x + 0.5f) : (1.0f / (1.0f + expf(-x)));  // g(h0)
#pragma unroll 4
  for (int j = 0; j < NCH; ++j) {
    size_t o = ((size_t)b * NCH + j) * cH + h;
    hin[o] = hc;
    hc = Qb[o] + Pb[o] * hc;
  }
}

// NOTE: gbuf aliases out (g stored in d_out region) -> no __restrict__ on those.
__global__ void scan_write_kernel(const float* __restrict__ cbuf, const float* gbuf,
                                  const float* __restrict__ hin, float* out) {
  const int bc = blockIdx.x;
  const int b = bc / NCH, ch = bc % NCH;
  const int h4 = threadIdx.x * 4;
  f32x4 hc = *(const f32x4*)(hin + ((size_t)b * NCH + ch) * cH + h4);
  size_t base = ((size_t)b * cS + (size_t)ch * CLEN) * cH + h4;
#pragma unroll 4
  for (int i = 0; i < CLEN; ++i) {
    f32x4 c = *(const f32x4*)(cbuf + base + (size_t)i * cH);
    f32x4 g = *(const f32x4*)(gbuf + base + (size_t)i * cH);
    hc = c * hc + (1.0f - c) * g;
    *(f32x4*)(out + base + (size_t)i * cH) = hc;
  }
  if (ch == NCH - 1) {   // final hidden state -> second output
    *(f32x4*)(out + (size_t)cM * cH + (size_t)b * cH + h4) = hc;
  }
}

extern "C" void kernel_launch(void* const* d_in, const int* in_sizes, int n_in,
                              void* d_out, int out_size, void* d_ws, size_t ws_size,
                              hipStream_t stream) {
  const float* x   = (const float*)d_in[0];
  const float* h0  = (const float*)d_in[1];
  const float* Wz  = (const float*)d_in[2];
  const float* bz  = (const float*)d_in[3];
  const float* Wh  = (const float*)d_in[4];
  const float* bh  = (const float*)d_in[5];

  char* ws = (char*)d_ws;
  unsigned short* xh  = (unsigned short*)(ws);              // 32 MiB @ 0
  unsigned short* wwh = (unsigned short*)(ws + 33554432);   // 4 MiB
  unsigned short* wwl = (unsigned short*)(ws + 37748736);   // 4 MiB
  float* cbuf = (float*)(ws + 41943040);                    // 64 MiB
  float* Pb   = (float*)(ws + 109051904);                   // 1 MiB
  float* Qb   = (float*)(ws + 110100480);                   // 1 MiB
  float* hin  = (float*)(ws + 111149056);                   // 1 MiB (end ~107 MiB)
  float* out  = (float*)d_out;
  float* gbuf = out;   // g-values staged in d_out, overwritten by scan_write

  round_kernel<<<cM * cK / 1024, 256, 0, stream>>>(x, xh);
  split_kernel<<<cH * cK / 1024, 256, 0, stream>>>(Wz, wwh, wwl);
  split_kernel<<<cH * cK / 1024, 256, 0, stream>>>(Wh, wwh + (size_t)cH * cK, wwl + (size_t)cH * cK);
  gemm_kernel<<<dim3(cN / 128, cM / 128), 256, 0, stream>>>(xh, wwh, wwl, bz, bh, cbuf, gbuf);
  scan_chunk_kernel<<<cB * NCH, 256, 0, stream>>>(cbuf, gbuf, Pb, Qb);
  scan_prefix_kernel<<<cB * cH / 256, 256, 0, stream>>>(h0, Pb, Qb, hin);
  scan_write_kernel<<<cB * NCH, 256, 0, stream>>>(cbuf, gbuf, hin, out);
}